// Round 8
// baseline (247.013 us; speedup 1.0000x reference)
//
#include <hip/hip_runtime.h>
#include <hip/hip_bf16.h>

// y_i = x_i^T Q x_i + b^T x_i + c ; N=16384, D=1024, fp32.
// Round 8: the r2..r7 plateau (77-95us, MfmaUtil 14-18%) is the compiler's
// mandatory `s_waitcnt vmcnt(0)` before EVERY s_barrier: all mid-phase
// global loads (xv dot-operands, Q prefetch) are force-drained ~600-900 cyc
// after issue. Fix = more work per barrier: stage 64 Q^T rows per phase
// (8 barriers/block instead of 32; ~5k CU-cyc MFMA per phase) via bf16
// pre-pass + global_load_lds 16B DMA (zero staging regs/VALU; DMA issued
// after barrier p drains at p+1, ~5k cyc of flight). xv pipelined one tile
// ahead inside the barrier-free phase (620 cyc MFMA cover ~= L3 latency).
// A-frags stay AGPR-pinned (r1/r3 lessons); __launch_bounds__(256,2) keeps
// the 256-reg budget (128 AGPR + ~100 VGPR).

#define DD 1024
#define KH 256            // K per block (K-split 4)
#define KSTEP 8           // KH/32 MFMA k-steps per 16-n tile
#define NPH 8             // phases: 8 x 64 n-rows = 512 n per block
#define ROW_SH 256        // shorts per staged row (KH bf16)
#define BUF_SH (64 * ROW_SH)   // 32 KB per buffer

typedef short v8s __attribute__((ext_vector_type(8)));
typedef float v4f __attribute__((ext_vector_type(4)));

#define AS1(p) ((const __attribute__((address_space(1))) void*)(p))
#define AS3(p) ((__attribute__((address_space(3))) void*)(p))

__device__ __forceinline__ short f2b(float f) {
    union { __hip_bfloat16 h; short s; } u;
    u.h = __float2bfloat16(f);
    return u.s;
}

// ---- pre-pass: Q fp32 -> bf16 (row-major) into workspace ----
__global__ __launch_bounds__(256)
void convert_q(const float* __restrict__ Q, short* __restrict__ qb)
{
    const int i = blockIdx.x * 256 + threadIdx.x;   // 262144 float4s exactly
    const float4 f = ((const float4*)Q)[i];
    short4 s;
    s.x = f2b(f.x); s.y = f2b(f.y); s.z = f2b(f.z); s.w = f2b(f.w);
    ((short4*)qb)[i] = s;
}

template<bool PRE>
__device__ __forceinline__
void quad_body(const float* __restrict__ x, const float* __restrict__ Qf,
               const short* __restrict__ Qb, const float* __restrict__ bvec,
               const float* __restrict__ cptr, float* __restrict__ y)
{
    __shared__ short lq[2][BUF_SH];   // 2 x 32 KB (64 Q-rows x 256 k bf16)

    const int tid  = threadIdx.x;
    const int lane = tid & 63;
    const int wave = tid >> 6;
    const int quad = lane >> 4;
    const int l15  = lane & 15;

    const int seg  = blockIdx.x & 7;     // kq*2 + cs
    const int rblk = blockIdx.x >> 3;    // 0..63
    const int kq   = seg >> 1;           // K quarter
    const int cs   = seg & 1;            // column half

    const int row_base = rblk * 256 + wave * 64;   // 64 rows per wave
    const int kofs  = kq * KH;
    const int nbase = cs * 512;

    // ---- staging slot map: 2048 16B-slots per phase, 8 per thread ----
    // slot = i*256 + tid -> row = slot>>5 (0..63), cpos = slot&31.
    // LDS[row][cpos] holds global chunk (cpos ^ (row&7)) of that Q row
    // (XOR swizzle; DMA requires unpadded lane-contiguous dest).
    int srow[8], schunk[8];
    #pragma unroll
    for (int i = 0; i < 8; ++i) {
        const int slot = i * 256 + tid;
        const int r = slot >> 5, cp = slot & 31;
        srow[i] = r;
        schunk[i] = cp ^ (r & 7);
    }

    // ---- issue phase-0 staging (in flight across the A prologue) ----
    if (PRE) {
        #pragma unroll
        for (int i = 0; i < 8; ++i) {
            const short* src = Qb + (size_t)(nbase + srow[i]) * DD + kofs + schunk[i] * 8;
            __builtin_amdgcn_global_load_lds(AS1(src),
                AS3(&lq[0][(i * 256 + tid) * 8]), 16, 0, 0);
        }
    } else {
        #pragma unroll
        for (int i = 0; i < 8; ++i) {
            const float* src = Qf + (size_t)(nbase + srow[i]) * DD + kofs + schunk[i] * 8;
            const float4 f0 = *(const float4*)(src);
            const float4 f1 = *(const float4*)(src + 4);
            v8s t;
            t[0]=f2b(f0.x); t[1]=f2b(f0.y); t[2]=f2b(f0.z); t[3]=f2b(f0.w);
            t[4]=f2b(f1.x); t[5]=f2b(f1.y); t[6]=f2b(f1.z); t[7]=f2b(f1.w);
            *(v8s*)&lq[0][(i * 256 + tid) * 8] = t;
        }
    }

    // ---- A prologue: x[64 rows][kofs..kofs+256) bf16 frags in AGPRs ----
    // A layout (16x16x32): m = lane&15, k = quad*8 + j (8 contiguous bf16)
    v8s a[4][KSTEP];
    #pragma unroll
    for (int g = 0; g < 4; ++g) {
        const float* xr = x + (size_t)(row_base + g * 16 + l15) * DD + kofs + quad * 8;
        #pragma unroll
        for (int s = 0; s < KSTEP; ++s) {
            const float4 f0 = *(const float4*)(xr + s * 32);
            const float4 f1 = *(const float4*)(xr + s * 32 + 4);
            v8s t;
            t[0]=f2b(f0.x); t[1]=f2b(f0.y); t[2]=f2b(f0.z); t[3]=f2b(f0.w);
            t[4]=f2b(f1.x); t[5]=f2b(f1.y); t[6]=f2b(f1.z); t[7]=f2b(f1.w);
            a[g][s] = t;
            asm volatile("" : "+a"(a[g][s]));   // pin to AGPR
        }
    }

    float acc[4][4];
    #pragma unroll
    for (int g = 0; g < 4; ++g)
        #pragma unroll
        for (int r = 0; r < 4; ++r) acc[g][r] = 0.f;

    for (int p = 0; p < NPH; ++p) {
        __syncthreads();   // buf p&1 staged; prior readers of other buf done

        // ---- issue next phase's staging into the other buffer ----
        if (p + 1 < NPH) {
            const size_t nb = (size_t)(nbase + (p + 1) * 64) * DD + kofs;
            short* dst = &lq[(p + 1) & 1][0];
            if (PRE) {
                #pragma unroll
                for (int i = 0; i < 8; ++i) {
                    const short* src = Qb + nb + (size_t)srow[i] * DD + schunk[i] * 8;
                    __builtin_amdgcn_global_load_lds(AS1(src),
                        AS3(&dst[(i * 256 + tid) * 8]), 16, 0, 0);
                }
            } else {
                #pragma unroll
                for (int i = 0; i < 8; ++i) {
                    const float* src = Qf + nb + (size_t)srow[i] * DD + schunk[i] * 8;
                    const float4 f0 = *(const float4*)(src);
                    const float4 f1 = *(const float4*)(src + 4);
                    v8s t;
                    t[0]=f2b(f0.x); t[1]=f2b(f0.y); t[2]=f2b(f0.z); t[3]=f2b(f0.w);
                    t[4]=f2b(f1.x); t[5]=f2b(f1.y); t[6]=f2b(f1.z); t[7]=f2b(f1.w);
                    *(v8s*)&dst[(i * 256 + tid) * 8] = t;
                }
            }
        }

        // ---- 4 tiles of 16 n each, no barriers in between; xv pipelined --
        const short* buf = &lq[p & 1][0];

        float xva[4][4], xvb[4][4];
        float bna, bnb;
        {   // preload tile 0 operands
            const int n = nbase + p * 64 + l15;
            bna = (kq == 0) ? bvec[n] : 0.f;
            const float* xc = x + (size_t)(row_base + quad * 4) * DD + n;
            #pragma unroll
            for (int g = 0; g < 4; ++g)
                #pragma unroll
                for (int r = 0; r < 4; ++r)
                    xva[g][r] = xc[(size_t)(g * 16 + r) * DD];
        }

        #pragma unroll
        for (int tau = 0; tau < 4; ++tau) {
            // prefetch tile tau+1 operands (covered by this tile's MFMAs)
            if (tau < 3) {
                const int n = nbase + p * 64 + (tau + 1) * 16 + l15;
                bnb = (kq == 0) ? bvec[n] : 0.f;
                const float* xc = x + (size_t)(row_base + quad * 4) * DD + n;
                #pragma unroll
                for (int g = 0; g < 4; ++g)
                    #pragma unroll
                    for (int r = 0; r < 4; ++r)
                        xvb[g][r] = xc[(size_t)(g * 16 + r) * DD];
            }

            v4f cf[4];
            #pragma unroll
            for (int g = 0; g < 4; ++g) cf[g] = (v4f){0.f, 0.f, 0.f, 0.f};

            #pragma unroll
            for (int s = 0; s < KSTEP; ++s) {
                // logical chunk = s*4 + quad, stored at chunk ^ (row&7)
                const int phys = (s * 4 + quad) ^ (l15 & 7);
                const v8s bf = *(const v8s*)&buf[(tau * 16 + l15) * ROW_SH + phys * 8];
                #pragma unroll
                for (int g = 0; g < 4; ++g)
                    cf[g] = __builtin_amdgcn_mfma_f32_16x16x32_bf16(a[g][s], bf, cf[g], 0, 0, 0);
            }

            // fused dot: C layout col = lane&15, row = quad*4 + reg
            #pragma unroll
            for (int g = 0; g < 4; ++g)
                #pragma unroll
                for (int r = 0; r < 4; ++r)
                    acc[g][r] += (cf[g][r] + bna) * xva[g][r];

            // rotate pipelined operands
            bna = bnb;
            #pragma unroll
            for (int g = 0; g < 4; ++g)
                #pragma unroll
                for (int r = 0; r < 4; ++r) xva[g][r] = xvb[g][r];
        }
    }

    // ---- reduce across the 16 lanes of each quad, atomic into y ----
    const float cc = (seg == 0) ? cptr[0] : 0.f;  // c added once per row
    #pragma unroll
    for (int g = 0; g < 4; ++g) {
        #pragma unroll
        for (int r = 0; r < 4; ++r) {
            float v = acc[g][r];
            v += __shfl_xor(v, 1); v += __shfl_xor(v, 2);
            v += __shfl_xor(v, 4); v += __shfl_xor(v, 8);
            if (l15 == 0)
                atomicAdd(&y[row_base + g * 16 + quad * 4 + r], v + cc);
        }
    }
}

__global__ __launch_bounds__(256, 2)
void quad_pre(const float* __restrict__ x, const short* __restrict__ Qb,
              const float* __restrict__ bvec, const float* __restrict__ cptr,
              float* __restrict__ y)
{
    quad_body<true>(x, nullptr, Qb, bvec, cptr, y);
}

__global__ __launch_bounds__(256, 2)
void quad_fp32(const float* __restrict__ x, const float* __restrict__ Qf,
               const float* __restrict__ bvec, const float* __restrict__ cptr,
               float* __restrict__ y)
{
    quad_body<false>(x, Qf, nullptr, bvec, cptr, y);
}

extern "C" void kernel_launch(void* const* d_in, const int* in_sizes, int n_in,
                              void* d_out, int out_size, void* d_ws, size_t ws_size,
                              hipStream_t stream)
{
    const float* x = (const float*)d_in[0];
    const float* Q = (const float*)d_in[1];
    const float* b = (const float*)d_in[2];
    const float* c = (const float*)d_in[3];
    float* y = (float*)d_out;

    hipMemsetAsync(y, 0, (size_t)out_size * sizeof(float), stream);

    if (ws_size >= (size_t)DD * DD * sizeof(short)) {
        short* qb = (short*)d_ws;
        convert_q<<<dim3(1024), dim3(256), 0, stream>>>(Q, qb);
        quad_pre<<<dim3(512), dim3(256), 0, stream>>>(x, qb, b, c, y);
    } else {
        quad_fp32<<<dim3(512), dim3(256), 0, stream>>>(x, Q, b, c, y);
    }
}

// Round 9
// 203.502 us; speedup vs baseline: 1.2138x; 1.2138x over previous
//
#include <hip/hip_runtime.h>
#include <hip/hip_bf16.h>

// y_i = x_i^T Q x_i + b^T x_i + c ; N=16384, D=1024, fp32.
// Round 9: abandon the A-resident fused design (r2-r8 plateau 76-95us at
// 14-18% MfmaUtil; 128-AGPR A-frags leave no VGPRs to pipeline -> either
// spill (r3/r8) or exposed latency). New structure = m97-style 128x128 tile
// GEMM (documented 36% MfmaUtil): C-tile = (x Q^T)-subtile; acc = 64 AGPR
// only; fused dot becomes a ONE-TIME epilogue per block:
//   y[m] += sum_n (C[m][n] + b[n]) * x[m][n]   (+c once), atomicAdd.
// BK=32, double-buffered 32 KB LDS. B = Q^T rows from bf16 pre-pass via
// global_load_lds DMA + XOR chunk swizzle (r7/r8-proven). A = x staged
// fp32->bf16 via register path, pipelined one iter ahead. (256,3) ->
// 12 waves/CU, 3 blocks/CU. Grid = 128 mb x 8 nb = 1024 blocks.

#define DD 1024

typedef short v8s __attribute__((ext_vector_type(8)));
typedef float v4f __attribute__((ext_vector_type(4)));

#define AS1(p) ((const __attribute__((address_space(1))) void*)(p))
#define AS3(p) ((__attribute__((address_space(3))) void*)(p))

__device__ __forceinline__ short f2b(float f) {
    union { __hip_bfloat16 h; short s; } u;
    u.h = __float2bfloat16(f);
    return u.s;
}

__device__ __forceinline__ v8s pack8(const float4& a, const float4& b) {
    v8s t;
    t[0]=f2b(a.x); t[1]=f2b(a.y); t[2]=f2b(a.z); t[3]=f2b(a.w);
    t[4]=f2b(b.x); t[5]=f2b(b.y); t[6]=f2b(b.z); t[7]=f2b(b.w);
    return t;
}

// ---- pre-pass: Q fp32 -> bf16 (row-major) into workspace ----
__global__ __launch_bounds__(256)
void convert_q(const float* __restrict__ Q, short* __restrict__ qb)
{
    const int i = blockIdx.x * 256 + threadIdx.x;   // 262144 float4 exactly
    const float4 f = ((const float4*)Q)[i];
    short4 s;
    s.x=f2b(f.x); s.y=f2b(f.y); s.z=f2b(f.z); s.w=f2b(f.w);
    ((short4*)qb)[i] = s;
}

template<bool PRE>
__device__ __forceinline__
void gemm_body(const float* __restrict__ x, const float* __restrict__ Qf,
               const short* __restrict__ Qb, const float* __restrict__ bvec,
               const float* __restrict__ cptr, float* __restrict__ y)
{
    // [buf][A=0/B=1][128 rows x 4 chunks x 8 shorts] = 2 x 2 x 8 KB = 32 KB
    __shared__ short lds[2][2][4096];

    const int tid  = threadIdx.x;
    const int lane = tid & 63;
    const int wave = tid >> 6;
    const int quad = lane >> 4;
    const int l15  = lane & 15;
    const int wr   = (wave >> 1) * 64;   // wave's row quadrant
    const int wc   = (wave & 1) * 64;    // wave's col quadrant

    const int mb = (int)blockIdx.x >> 3;     // 0..127
    const int nb = (int)blockIdx.x & 7;      // 0..7
    const int mbase = mb * 128;
    const int nbase = nb * 128;

    // ---- A staging map (register path, fp32 x -> bf16) ----
    // thread -> (row = tid>>1, khalf = tid&1): 16 floats = chunks {2h, 2h+1}
    // chunk c of row r stored at slot r*4 + (c ^ (r&3))  (bank swizzle)
    const int arow  = tid >> 1;
    const int ahalf = tid & 1;
    const float* xsrc = x + (size_t)(mbase + arow) * DD + ahalf * 16;
    const int aslot0 = arow * 4 + ((ahalf * 2)     ^ (arow & 3));
    const int aslot1 = arow * 4 + ((ahalf * 2 + 1) ^ (arow & 3));

    // ---- B staging map (DMA from bf16 Q^T rows; slot s holds global chunk
    //      (s&3)^(row&3) of Q row nbase+(s>>2)) ----
    const int bs0 = tid, bs1 = tid + 256;
    const short* qsrc0 = PRE ? Qb + (size_t)(nbase + (bs0 >> 2)) * DD
                                  + (((bs0 & 3) ^ ((bs0 >> 2) & 3)) * 8) : nullptr;
    const short* qsrc1 = PRE ? Qb + (size_t)(nbase + (bs1 >> 2)) * DD
                                  + (((bs1 & 3) ^ ((bs1 >> 2) & 3)) * 8) : nullptr;
    // fallback: register path from fp32 Q, same shape as the A path
    const float* qfsrc = PRE ? nullptr
                             : Qf + (size_t)(nbase + arow) * DD + ahalf * 16;

    // ---- accumulators: 4x4 tiles of 16x16 -> 64 AGPRs ----
    v4f acc[4][4];
    #pragma unroll
    for (int i = 0; i < 4; ++i)
        #pragma unroll
        for (int j = 0; j < 4; ++j) {
            acc[i][j] = (v4f){0.f, 0.f, 0.f, 0.f};
            asm volatile("" : "+a"(acc[i][j]));   // keep in AGPR file
        }

    // ---- prologue: stage k=0 into buf 0; prefetch k=32 ----
    float4 pfa[4], pfb[4];
    #pragma unroll
    for (int i = 0; i < 4; ++i) pfa[i] = *(const float4*)(xsrc + i * 4);
    if (PRE) {
        __builtin_amdgcn_global_load_lds(AS1(qsrc0), AS3(&lds[0][1][bs0 * 8]), 16, 0, 0);
        __builtin_amdgcn_global_load_lds(AS1(qsrc1), AS3(&lds[0][1][bs1 * 8]), 16, 0, 0);
    } else {
        #pragma unroll
        for (int i = 0; i < 4; ++i) pfb[i] = *(const float4*)(qfsrc + i * 4);
        *(v8s*)&lds[0][1][aslot0 * 8] = pack8(pfb[0], pfb[1]);
        *(v8s*)&lds[0][1][aslot1 * 8] = pack8(pfb[2], pfb[3]);
    }
    *(v8s*)&lds[0][0][aslot0 * 8] = pack8(pfa[0], pfa[1]);
    *(v8s*)&lds[0][0][aslot1 * 8] = pack8(pfa[2], pfa[3]);

    #pragma unroll
    for (int i = 0; i < 4; ++i) pfa[i] = *(const float4*)(xsrc + 32 + i * 4);
    if (!PRE) {
        #pragma unroll
        for (int i = 0; i < 4; ++i) pfb[i] = *(const float4*)(qfsrc + 32 + i * 4);
    }

    // ---- K loop: 32 iters of BK=32, double-buffered ----
    for (int it = 0; it < 32; ++it) {
        __syncthreads();   // buf it&1 staged; prior readers of other buf done

        const int cur = it & 1, nxt = cur ^ 1;
        if (it + 1 < 32) {
            const int kn = (it + 1) * 32;
            if (PRE) {
                __builtin_amdgcn_global_load_lds(AS1(qsrc0 + kn),
                    AS3(&lds[nxt][1][bs0 * 8]), 16, 0, 0);
                __builtin_amdgcn_global_load_lds(AS1(qsrc1 + kn),
                    AS3(&lds[nxt][1][bs1 * 8]), 16, 0, 0);
            } else {
                *(v8s*)&lds[nxt][1][aslot0 * 8] = pack8(pfb[0], pfb[1]);
                *(v8s*)&lds[nxt][1][aslot1 * 8] = pack8(pfb[2], pfb[3]);
            }
            // commit A (regs loaded one iter ago), then prefetch iter+2
            *(v8s*)&lds[nxt][0][aslot0 * 8] = pack8(pfa[0], pfa[1]);
            *(v8s*)&lds[nxt][0][aslot1 * 8] = pack8(pfa[2], pfa[3]);
            if (it + 2 < 32) {
                const int kn2 = (it + 2) * 32;
                #pragma unroll
                for (int i = 0; i < 4; ++i)
                    pfa[i] = *(const float4*)(xsrc + kn2 + i * 4);
                if (!PRE) {
                    #pragma unroll
                    for (int i = 0; i < 4; ++i)
                        pfb[i] = *(const float4*)(qfsrc + kn2 + i * 4);
                }
            }
        }

        // ---- compute: 4 A-frags + 4 B-frags -> 16 MFMA (2:1 mfma:ds_read)
        const short* Ab = &lds[cur][0][0];
        const short* Bb = &lds[cur][1][0];
        v8s af[4], bf[4];
        #pragma unroll
        for (int i = 0; i < 4; ++i) {
            const int rr = wr + i * 16 + l15;
            af[i] = *(const v8s*)&Ab[(rr * 4 + (quad ^ (rr & 3))) * 8];
        }
        #pragma unroll
        for (int j = 0; j < 4; ++j) {
            const int rr = wc + j * 16 + l15;
            bf[j] = *(const v8s*)&Bb[(rr * 4 + (quad ^ (rr & 3))) * 8];
        }
        #pragma unroll
        for (int i = 0; i < 4; ++i)
            #pragma unroll
            for (int j = 0; j < 4; ++j)
                acc[i][j] = __builtin_amdgcn_mfma_f32_16x16x32_bf16(af[i], bf[j], acc[i][j], 0, 0, 0);
    }

    // ---- epilogue (once per block): y[m] += sum_n (C[m][n]+b[n])*x[m][n] --
    // C layout: row = quad*4 + r, col = l15 (m89-verified)
    float bv[4];
    #pragma unroll
    for (int j = 0; j < 4; ++j) bv[j] = bvec[nbase + wc + j * 16 + l15];
    const float cc = (nb == 0 && wc == 0) ? cptr[0] : 0.f;

    #pragma unroll
    for (int i = 0; i < 4; ++i) {
        #pragma unroll
        for (int r = 0; r < 4; ++r) {
            const int m = mbase + wr + i * 16 + quad * 4 + r;
            const float* xr = x + (size_t)m * DD + nbase + wc + l15;
            float s = 0.f;
            #pragma unroll
            for (int j = 0; j < 4; ++j)
                s += (acc[i][j][r] + bv[j]) * xr[j * 16];
            s += __shfl_xor(s, 1); s += __shfl_xor(s, 2);
            s += __shfl_xor(s, 4); s += __shfl_xor(s, 8);
            if (l15 == 0) atomicAdd(&y[m], s + cc);
        }
    }
}

__global__ __launch_bounds__(256, 3)
void quad_pre(const float* __restrict__ x, const short* __restrict__ Qb,
              const float* __restrict__ bvec, const float* __restrict__ cptr,
              float* __restrict__ y)
{
    gemm_body<true>(x, nullptr, Qb, bvec, cptr, y);
}

__global__ __launch_bounds__(256, 2)
void quad_fp32(const float* __restrict__ x, const float* __restrict__ Qf,
               const float* __restrict__ bvec, const float* __restrict__ cptr,
               float* __restrict__ y)
{
    gemm_body<false>(x, Qf, nullptr, bvec, cptr, y);
}

extern "C" void kernel_launch(void* const* d_in, const int* in_sizes, int n_in,
                              void* d_out, int out_size, void* d_ws, size_t ws_size,
                              hipStream_t stream)
{
    const float* x = (const float*)d_in[0];
    const float* Q = (const float*)d_in[1];
    const float* b = (const float*)d_in[2];
    const float* c = (const float*)d_in[3];
    float* y = (float*)d_out;

    hipMemsetAsync(y, 0, (size_t)out_size * sizeof(float), stream);

    if (ws_size >= (size_t)DD * DD * sizeof(short)) {
        short* qb = (short*)d_ws;
        convert_q<<<dim3(1024), dim3(256), 0, stream>>>(Q, qb);
        quad_pre<<<dim3(1024), dim3(256), 0, stream>>>(x, qb, b, c, y);
    } else {
        quad_fp32<<<dim3(1024), dim3(256), 0, stream>>>(x, Q, b, c, y);
    }
}